// Round 24
// baseline (60.227 us; speedup 1.0000x reference)
//
#include <hip/hip_runtime.h>
#include <hip/hip_bf16.h>

#define NROWS 8192
#define DIM 512
#define BM 256
#define BN 256

typedef int   i32x4 __attribute__((ext_vector_type(4)));
typedef int   i32x8 __attribute__((ext_vector_type(8)));
typedef float f32x4 __attribute__((ext_vector_type(4)));

#define FP8_SCALE_1 0x7f7f7f7f   // E8M0 127 = 2^0 in all 4 bytes

__device__ __forceinline__ void gld_lds16(const void* g, void* l) {
  __builtin_amdgcn_global_load_lds(
      (__attribute__((address_space(1))) unsigned int*)(g),
      (__attribute__((address_space(3))) unsigned int*)(l),
      16, 0, 0);
}

// ---------- Phase 1: normalize -> fp8; A row-major, B fragment-linear ----------
// A (qf): row-major 512B/row (for swizzled gld_lds16 staging — r15 path).
// B (pf): fragment-linear 2KB lane-major blocks (r22/r23 path, proven):
//   ((((panel*4+kt)*4+wcq)*4+nf)*2+sel)*1024 + laneT*16 + byte.
// 512 blocks x 256 thr; block owns 16 rows; unit-stride float4 reads.
__global__ __launch_bounds__(256) void prep_k(
    const float* __restrict__ q, const float* __restrict__ p,
    char* __restrict__ qf, char* __restrict__ pf,
    float* __restrict__ diag) {
  __shared__ char ldsp[16 * 528];
  const int tid = threadIdx.x;
  const int blk = blockIdx.x;
  const int rr = tid >> 4;              // row in group
  const int cs = tid & 15;              // 16 threads per row
  const int i  = blk * 16 + rr;         // global row
  const float4* qr = (const float4*)(q + (size_t)i * DIM);
  const float4* pr = (const float4*)(p + (size_t)i * DIM);

  float4 qv[8], pv[8];
  float ssq = 0.0f, ssp = 0.0f, dt = 0.0f;
  #pragma unroll
  for (int jj = 0; jj < 8; ++jj) {
    qv[jj] = qr[jj * 16 + cs];
    pv[jj] = pr[jj * 16 + cs];
    ssq += qv[jj].x*qv[jj].x + qv[jj].y*qv[jj].y + qv[jj].z*qv[jj].z + qv[jj].w*qv[jj].w;
    ssp += pv[jj].x*pv[jj].x + pv[jj].y*pv[jj].y + pv[jj].z*pv[jj].z + pv[jj].w*pv[jj].w;
    dt  += qv[jj].x*pv[jj].x + qv[jj].y*pv[jj].y + qv[jj].z*pv[jj].z + qv[jj].w*pv[jj].w;
  }
  #pragma unroll
  for (int m = 1; m < 16; m <<= 1) {
    ssq += __shfl_xor(ssq, m, 64);
    ssp += __shfl_xor(ssp, m, 64);
    dt  += __shfl_xor(dt,  m, 64);
  }
  const float invq = 1.0f / fmaxf(sqrtf(ssq), 1e-8f);
  const float invp = 1.0f / fmaxf(sqrtf(ssp), 1e-8f);
  if (cs == 0) diag[i] = dt * invq * invp * 20.0f;

  #pragma unroll
  for (int jj = 0; jj < 8; ++jj) {
    int rq = 0, rp = 0;
    rq = __builtin_amdgcn_cvt_pk_fp8_f32(qv[jj].x * invq, qv[jj].y * invq, rq, false);
    rq = __builtin_amdgcn_cvt_pk_fp8_f32(qv[jj].z * invq, qv[jj].w * invq, rq, true);
    rp = __builtin_amdgcn_cvt_pk_fp8_f32(pv[jj].x * invp, pv[jj].y * invp, rp, false);
    rp = __builtin_amdgcn_cvt_pk_fp8_f32(pv[jj].z * invp, pv[jj].w * invp, rp, true);
    // A: row-major direct write (k-bytes jj*64 + cs*4 of row i)
    *(unsigned int*)(qf + (size_t)i * 512 + jj * 64 + cs * 4) = (unsigned int)rq;
    // B: stage in padded LDS for fragment gather
    *(unsigned int*)(ldsp + rr * 528 + jj * 64 + cs * 4) = (unsigned int)rp;
  }
  __syncthreads();

  // B: coalesced fragment-block writes (512 x 16B chunks)
  const int panel = blk >> 4, rg = blk & 15;
  #pragma unroll
  for (int u = 0; u < 2; ++u) {
    const int o = 2 * tid + u;
    const int kt = o >> 7, sel = (o >> 6) & 1, laneT = o & 63;
    const int rrs = laneT & 15;
    const int srcoff = kt * 128 + (laneT >> 4) * 32 + sel * 16;
    const i32x4 vb = *(const i32x4*)(ldsp + rrs * 528 + srcoff);
    const size_t baddr =
        ((((size_t)(panel * 4 + kt) * 4 + (rg >> 2)) * 4 + (rg & 3)) * 2 + sel) * 1024
        + laneT * 16;
    *(i32x4*)(pf + baddr) = vb;
  }
}

// ---------- Phase 2: MX-fp8 GEMM, SPLIT-PIPE operands ----------
// A (128KB/iter, 4x-amplified) via LDS: r15's swizzled gld_lds16 staging +
// ds_read_b128 — ~1000cy read + 256cy write on the LDS pipe.
// B (64KB/iter, 2x-amplified) DIRECT from global fragment-linear — 8 fully-
// coalesced 1024B loads/wave, ~1024cy on the L1 pipe.
// The two pipes drain CONCURRENTLY (r15/r22 each used one pipe for all 192KB
// — both converged at 6900cy/iter; this splits the load). One barrier/iter
// (A dbuf publish). 256 blocks (1/CU), 8 waves (2Mx4N), 128x64/wave,
// transposed acc, r13 L2-resident map (3MB/XCD).
__device__ __forceinline__ i32x8 rd32(const char* base, int c0, int sw) {
  const i32x4 lo = *(const i32x4*)(base + ((c0     ) ^ sw));
  const i32x4 hi = *(const i32x4*)(base + ((c0 + 16) ^ sw));
  return __builtin_shufflevector(lo, hi, 0, 1, 2, 3, 4, 5, 6, 7);
}
// stage one 128-row half of A (2 gld_lds per thread, 512 threads)
__device__ __forceinline__ void stage_half(const char* __restrict__ g, char* dstb,
                                           int rowbase, int h, int tid, int kb) {
  #pragma unroll
  for (int j = 0; j < 2; ++j) {
    const int idx = j * 512 + tid;
    const int rl = idx >> 3;
    const int scb = ((idx & 7) << 4) ^ ((rl & 7) << 4);
    gld_lds16(g + (size_t)(rowbase + h * 128 + rl) * 512 + kb + scb,
              dstb + h * 16384 + idx * 16);
  }
}

__global__ __launch_bounds__(512, 2) void gemm_lse_k(
    const char* __restrict__ qf, const char* __restrict__ pf,
    float* __restrict__ partial) {
  __shared__ __attribute__((aligned(16))) char lds[69632];  // A dbuf 2x32KB + 4KB psum
  const int tid = threadIdx.x;
  const int lane = tid & 63, wid = tid >> 6;
  const int wr = wid >> 2, wc = wid & 3;        // 2M x 4N wave grid
  const int l15 = lane & 15, l4 = lane >> 4;
  const int sw = (l15 & 7) << 4;
  const int c0 = l4 * 32;
  const int b = blockIdx.x;
  const int g = b & 7;                          // XCD (round-robin dispatch)
  const int j = b >> 3;                         // 0..31 within XCD
  const int bm = ((g & 3) * 8 + (j & 7)) * BM;         // A panel (4 blocks share)
  const int bnset = (g >> 2) * 16 + (j >> 3) * 4;      // 4 B panels (8 share)
  float* psum = (float*)(lds + 65536);
  const int aOff = wr * 16384 + l15 * 128;      // A in LDS: + mf*2048 (+8192 half)
  const char* pBase = pf + (size_t)lane * 16;   // B fragment-linear

  f32x4 acc[4][8] = {};                         // [nb][am], transposed
  i32x8 af0[4], af1[4], bf[4];

  // Prologue: stage A tile 0, drain, barrier.
  stage_half(qf, lds, bm, 0, tid, 0);
  stage_half(qf, lds, bm, 1, tid, 0);
  asm volatile("s_waitcnt vmcnt(0)" ::: "memory");
  __builtin_amdgcn_s_barrier();

  #pragma unroll 1
  for (int tt = 0; tt < 16; ++tt) {
    const int kt = tt & 3, t = tt >> 2;
    char* rb = lds + (tt & 1) * 32768;
    char* sb = lds + ((tt + 1) & 1) * 32768;
    const int kbn = ((tt + 1) & 3) * 128;

    // B: 8 fully-coalesced 1024B direct loads (L1 pipe)
    const char* bB = pBase + (size_t)(((bnset + t) * 4 + kt) * 4 + wc) * 8192;
    #pragma unroll
    for (int nf = 0; nf < 4; ++nf) {
      const i32x4 lo = *(const i32x4*)(bB + nf * 2048);
      const i32x4 hi = *(const i32x4*)(bB + nf * 2048 + 1024);
      bf[nf] = __builtin_shufflevector(lo, hi, 0, 1, 2, 3, 4, 5, 6, 7);
    }
    // A: 16 ds_read_b128 from swizzled LDS (LDS pipe)
    #pragma unroll
    for (int mf = 0; mf < 4; ++mf)
      af0[mf] = rd32(rb + aOff + mf * 2048, c0, sw);
    #pragma unroll
    for (int mf = 0; mf < 4; ++mf)
      af1[mf] = rd32(rb + aOff + 8192 + mf * 2048, c0, sw);
    // stage next A tile into other buffer
    if (tt < 15) {
      stage_half(qf, sb, bm, 0, tid, kbn);
      stage_half(qf, sb, bm, 1, tid, kbn);
    }

    __builtin_amdgcn_s_setprio(1);
    #pragma unroll
    for (int nb = 0; nb < 4; ++nb) {
      #pragma unroll
      for (int mf = 0; mf < 4; ++mf)
        acc[nb][mf] = __builtin_amdgcn_mfma_scale_f32_16x16x128_f8f6f4(
            bf[nb], af0[mf], acc[nb][mf], 0, 0, 0, FP8_SCALE_1, 0, FP8_SCALE_1);
      #pragma unroll
      for (int mf = 0; mf < 4; ++mf)
        acc[nb][4 + mf] = __builtin_amdgcn_mfma_scale_f32_16x16x128_f8f6f4(
            bf[nb], af1[mf], acc[nb][4 + mf], 0, 0, 0, FP8_SCALE_1, 0, FP8_SCALE_1);
    }
    __builtin_amdgcn_s_setprio(0);

    asm volatile("s_waitcnt vmcnt(0)" ::: "memory");  // A stage landed
    __builtin_amdgcn_s_barrier();                     // publish sb

    if ((tt & 3) == 3) {
      // ---- flush output tile t: exp(20c-20) + row-sum + store ----
      // Lane rows m = wr*128 + am*16 + l15; cols n = wc*64 + nb*16 + l4*4 + r.
      const int bxc = bnset + t;
      #pragma unroll
      for (int am = 0; am < 8; ++am) {
        float s = 0.0f;
        #pragma unroll
        for (int nb = 0; nb < 4; ++nb)
          #pragma unroll
          for (int r = 0; r < 4; ++r)
            s += __expf(acc[nb][am][r] * 20.0f - 20.0f);
        s += __shfl_xor(s, 16, 64);
        s += __shfl_xor(s, 32, 64);
        if (l4 == 0)
          psum[wc * 256 + wr * 128 + am * 16 + l15] = s;
      }
      asm volatile("s_waitcnt lgkmcnt(0)" ::: "memory");
      __builtin_amdgcn_s_barrier();
      if (tid < 256)
        partial[(size_t)(bm + tid) * 32 + bxc] =
            psum[tid] + psum[256 + tid] + psum[512 + tid] + psum[768 + tid];
      #pragma unroll
      for (int nb = 0; nb < 4; ++nb)
        #pragma unroll
        for (int am = 0; am < 8; ++am)
          acc[nb][am] = f32x4{0.0f, 0.0f, 0.0f, 0.0f};
    }
  }
}

// ---------- Phase 3a: per-row loss ----------
__global__ __launch_bounds__(256) void rowloss_k(
    const float* __restrict__ partial, const float* __restrict__ diag,
    float* __restrict__ rowloss) {
  const int i = blockIdx.x * 256 + threadIdx.x;
  const float4* pr = (const float4*)(partial + (size_t)i * 32);
  float s = 0.0f;
  #pragma unroll
  for (int c = 0; c < 8; ++c) {
    const float4 v = pr[c];
    s += v.x + v.y + v.z + v.w;
  }
  rowloss[i] = __logf(s) + 20.0f - diag[i];
}

// ---------- Phase 3b: mean ----------
__global__ __launch_bounds__(1024) void final_k(
    const float* __restrict__ rowloss, float* __restrict__ out) {
  const int t = threadIdx.x;
  float s = 0.0f;
  #pragma unroll
  for (int j = 0; j < 8; ++j) s += rowloss[t + j * 1024];
  #pragma unroll
  for (int m = 1; m < 64; m <<= 1) s += __shfl_xor(s, m, 64);
  __shared__ float red[16];
  if ((t & 63) == 0) red[t >> 6] = s;
  __syncthreads();
  if (t == 0) {
    float acc = 0.0f;
    #pragma unroll
    for (int w = 0; w < 16; ++w) acc += red[w];
    out[0] = acc * (1.0f / (float)NROWS);
  }
}

extern "C" void kernel_launch(void* const* d_in, const int* in_sizes, int n_in,
                              void* d_out, int out_size, void* d_ws, size_t ws_size,
                              hipStream_t stream) {
  const float* q = (const float*)d_in[0];
  const float* p = (const float*)d_in[1];
  char* w = (char*)d_ws;
  char* qf = w;                                               // 4 MB fp8 A rows
  char* pf = w + 4194304;                                     // 4 MB fp8 B frags
  float* partial    = (float*)(w + 8388608);                  // 1 MB [8192][32]
  float* diag       = (float*)(w + 9437184);                  // 32 KB
  float* rowloss    = (float*)(w + 9437184 + 32768);          // 32 KB
  float* out = (float*)d_out;

  prep_k<<<NROWS / 16, 256, 0, stream>>>(q, p, qf, pf, diag);
  gemm_lse_k<<<256, 512, 0, stream>>>(qf, pf, partial);
  rowloss_k<<<NROWS / 256, 256, 0, stream>>>(partial, diag, rowloss);
  final_k<<<1, 1024, 0, stream>>>(rowloss, out);
}

// Round 25
// 57.330 us; speedup vs baseline: 1.0505x; 1.0505x over previous
//
#include <hip/hip_runtime.h>
#include <hip/hip_bf16.h>

#define NROWS 8192
#define DIM 512
#define BM 256
#define BN 256

typedef int   i32x4 __attribute__((ext_vector_type(4)));
typedef int   i32x8 __attribute__((ext_vector_type(8)));
typedef float f32x4 __attribute__((ext_vector_type(4)));

#define FP8_SCALE_1 0x7f7f7f7f   // E8M0 127 = 2^0 in all 4 bytes

// ---------- Phase 1: normalize -> fp8 -> FRAGMENT-LINEAR layout, coalesced ----------
// (r23 prep, proven absmax 0.0, ~7.3us) Output layout, 2KB lane-major blocks:
//  A: ((((panel*4+kt)*2+wrhalf)*8+mf)*2+sel)*1024 + laneT*16 + byte
//  B: ((((panel*4+kt)*4+wc   )*4+nf)*2+sel)*1024 + laneT*16 + byte
__global__ __launch_bounds__(256) void prep_k(
    const float* __restrict__ q, const float* __restrict__ p,
    char* __restrict__ qf, char* __restrict__ pf,
    float* __restrict__ diag) {
  __shared__ char ldsq[16 * 528];
  __shared__ char ldsp[16 * 528];
  const int tid = threadIdx.x;
  const int blk = blockIdx.x;
  const int rr = tid >> 4;              // row in group
  const int cs = tid & 15;              // 16 threads per row
  const int i  = blk * 16 + rr;         // global row
  const float4* qr = (const float4*)(q + (size_t)i * DIM);
  const float4* pr = (const float4*)(p + (size_t)i * DIM);

  float4 qv[8], pv[8];
  float ssq = 0.0f, ssp = 0.0f, dt = 0.0f;
  #pragma unroll
  for (int jj = 0; jj < 8; ++jj) {
    qv[jj] = qr[jj * 16 + cs];          // unit-stride across 16 lanes
    pv[jj] = pr[jj * 16 + cs];
    ssq += qv[jj].x*qv[jj].x + qv[jj].y*qv[jj].y + qv[jj].z*qv[jj].z + qv[jj].w*qv[jj].w;
    ssp += pv[jj].x*pv[jj].x + pv[jj].y*pv[jj].y + pv[jj].z*pv[jj].z + pv[jj].w*pv[jj].w;
    dt  += qv[jj].x*pv[jj].x + qv[jj].y*pv[jj].y + qv[jj].z*pv[jj].z + qv[jj].w*pv[jj].w;
  }
  #pragma unroll
  for (int m = 1; m < 16; m <<= 1) {
    ssq += __shfl_xor(ssq, m, 64);
    ssp += __shfl_xor(ssp, m, 64);
    dt  += __shfl_xor(dt,  m, 64);
  }
  const float invq = 1.0f / fmaxf(sqrtf(ssq), 1e-8f);
  const float invp = 1.0f / fmaxf(sqrtf(ssp), 1e-8f);
  if (cs == 0) diag[i] = dt * invq * invp * 20.0f;

  #pragma unroll
  for (int jj = 0; jj < 8; ++jj) {
    int rq = 0, rp = 0;
    rq = __builtin_amdgcn_cvt_pk_fp8_f32(qv[jj].x * invq, qv[jj].y * invq, rq, false);
    rq = __builtin_amdgcn_cvt_pk_fp8_f32(qv[jj].z * invq, qv[jj].w * invq, rq, true);
    rp = __builtin_amdgcn_cvt_pk_fp8_f32(pv[jj].x * invp, pv[jj].y * invp, rp, false);
    rp = __builtin_amdgcn_cvt_pk_fp8_f32(pv[jj].z * invp, pv[jj].w * invp, rp, true);
    *(unsigned int*)(ldsq + rr * 528 + jj * 64 + cs * 4) = (unsigned int)rq;
    *(unsigned int*)(ldsp + rr * 528 + jj * 64 + cs * 4) = (unsigned int)rp;
  }
  __syncthreads();

  // coalesced fragment-block writes: 512 x 16B chunks (4kt x 2sel x 64laneT)
  const int panel = blk >> 4, rg = blk & 15;
  #pragma unroll
  for (int u = 0; u < 2; ++u) {
    const int o = 2 * tid + u;
    const int kt = o >> 7, sel = (o >> 6) & 1, laneT = o & 63;
    const int rrs = laneT & 15;
    const int srcoff = kt * 128 + (laneT >> 4) * 32 + sel * 16;
    const i32x4 va = *(const i32x4*)(ldsq + rrs * 528 + srcoff);
    const size_t aaddr =
        ((((size_t)(panel * 4 + kt) * 2 + (rg >> 3)) * 8 + (rg & 7)) * 2 + sel) * 1024
        + laneT * 16;
    *(i32x4*)(qf + aaddr) = va;
    const i32x4 vb = *(const i32x4*)(ldsp + rrs * 528 + srcoff);
    const size_t baddr =
        ((((size_t)(panel * 4 + kt) * 4 + (rg >> 2)) * 4 + (rg & 3)) * 2 + sel) * 1024
        + laneT * 16;
    *(i32x4*)(pf + baddr) = vb;
  }
}

// ---------- Phase 2: MX-fp8 GEMM, fragment-linear DIRECT loads (r22, 45.7us) ----------
// 256 persistent blocks (1/CU), 8 waves (2Mx4N), 128x64 out/wave, transposed
// accumulators (acc lands in AGPRs: VGPR_Count 120). Zero LDS operands, zero
// K-loop barriers; all loads base+lane*16 fully coalesced 1024B; L2-resident
// XCD map (3MB/XCD, FETCH 12.3MB proven). Structural wall at ~6900cy/iter
// (10 variants converge) — best measured configuration.
__global__ __launch_bounds__(512, 2) void gemm_lse_k(
    const char* __restrict__ qf, const char* __restrict__ pf,
    float* __restrict__ partial) {
  __shared__ float psum[1024];                  // only LDS: 4KB flush buffer
  const int tid = threadIdx.x;
  const int lane = tid & 63, wid = tid >> 6;
  const int wr = wid >> 2, wc = wid & 3;        // 2M x 4N wave grid
  const int l15 = lane & 15, l4 = lane >> 4;
  const int b = blockIdx.x;
  const int g = b & 7;                          // XCD (round-robin dispatch)
  const int j = b >> 3;                         // 0..31 within XCD
  const int panelA = (g & 3) * 8 + (j & 7);     // A panel (4 blocks share)
  const int bnset  = (g >> 2) * 16 + (j >> 3) * 4;   // 4 B panels (8 share)
  const int bm = panelA * BM;
  const char* aPanel = qf + (size_t)panelA * 131072 + (size_t)lane * 16;
  const char* pBase  = pf + (size_t)lane * 16;

  f32x4 acc[4][8] = {};                         // [nb][am], transposed
  i32x8 af[8], bf[4];

  #pragma unroll 1
  for (int tt = 0; tt < 16; ++tt) {
    const int kt = tt & 3, t = tt >> 2;
    const char* aB = aPanel + (size_t)(kt * 2 + wr) * 16384;
    const char* bB = pBase +
        (size_t)(((bnset + t) * 4 + kt) * 4 + wc) * 8192;

    // 24 fully-coalesced 1024B loads (12 frags x lo/hi)
    #pragma unroll
    for (int mf = 0; mf < 8; ++mf) {
      const i32x4 lo = *(const i32x4*)(aB + mf * 2048);
      const i32x4 hi = *(const i32x4*)(aB + mf * 2048 + 1024);
      af[mf] = __builtin_shufflevector(lo, hi, 0, 1, 2, 3, 4, 5, 6, 7);
    }
    #pragma unroll
    for (int nf = 0; nf < 4; ++nf) {
      const i32x4 lo = *(const i32x4*)(bB + nf * 2048);
      const i32x4 hi = *(const i32x4*)(bB + nf * 2048 + 1024);
      bf[nf] = __builtin_shufflevector(lo, hi, 0, 1, 2, 3, 4, 5, 6, 7);
    }

    __builtin_amdgcn_s_setprio(1);
    #pragma unroll
    for (int nb = 0; nb < 4; ++nb)
      #pragma unroll
      for (int am = 0; am < 8; ++am)
        acc[nb][am] = __builtin_amdgcn_mfma_scale_f32_16x16x128_f8f6f4(
            bf[nb], af[am], acc[nb][am], 0, 0, 0, FP8_SCALE_1, 0, FP8_SCALE_1);
    __builtin_amdgcn_s_setprio(0);

    if ((tt & 3) == 3) {
      // ---- flush output tile t: exp(20c-20) + row-sum + store ----
      // Lane rows m = wr*128 + am*16 + l15; cols n = wc*64 + nb*16 + l4*4 + r.
      const int bxc = bnset + t;
      #pragma unroll
      for (int am = 0; am < 8; ++am) {
        float s = 0.0f;
        #pragma unroll
        for (int nb = 0; nb < 4; ++nb)
          #pragma unroll
          for (int r = 0; r < 4; ++r)
            s += __expf(acc[nb][am][r] * 20.0f - 20.0f);
        s += __shfl_xor(s, 16, 64);
        s += __shfl_xor(s, 32, 64);
        if (l4 == 0)
          psum[wc * 256 + wr * 128 + am * 16 + l15] = s;
      }
      __syncthreads();
      if (tid < 256)
        partial[(size_t)(bm + tid) * 32 + bxc] =
            psum[tid] + psum[256 + tid] + psum[512 + tid] + psum[768 + tid];
      __syncthreads();      // psum safe before next tile's writes
      #pragma unroll
      for (int nb = 0; nb < 4; ++nb)
        #pragma unroll
        for (int am = 0; am < 8; ++am)
          acc[nb][am] = f32x4{0.0f, 0.0f, 0.0f, 0.0f};
    }
  }
}

// ---------- Phase 3a: per-row loss ----------
__global__ __launch_bounds__(256) void rowloss_k(
    const float* __restrict__ partial, const float* __restrict__ diag,
    float* __restrict__ rowloss) {
  const int i = blockIdx.x * 256 + threadIdx.x;
  const float4* pr = (const float4*)(partial + (size_t)i * 32);
  float s = 0.0f;
  #pragma unroll
  for (int c = 0; c < 8; ++c) {
    const float4 v = pr[c];
    s += v.x + v.y + v.z + v.w;
  }
  rowloss[i] = __logf(s) + 20.0f - diag[i];
}

// ---------- Phase 3b: mean ----------
__global__ __launch_bounds__(1024) void final_k(
    const float* __restrict__ rowloss, float* __restrict__ out) {
  const int t = threadIdx.x;
  float s = 0.0f;
  #pragma unroll
  for (int j = 0; j < 8; ++j) s += rowloss[t + j * 1024];
  #pragma unroll
  for (int m = 1; m < 64; m <<= 1) s += __shfl_xor(s, m, 64);
  __shared__ float red[16];
  if ((t & 63) == 0) red[t >> 6] = s;
  __syncthreads();
  if (t == 0) {
    float acc = 0.0f;
    #pragma unroll
    for (int w = 0; w < 16; ++w) acc += red[w];
    out[0] = acc * (1.0f / (float)NROWS);
  }
}

extern "C" void kernel_launch(void* const* d_in, const int* in_sizes, int n_in,
                              void* d_out, int out_size, void* d_ws, size_t ws_size,
                              hipStream_t stream) {
  const float* q = (const float*)d_in[0];
  const float* p = (const float*)d_in[1];
  char* w = (char*)d_ws;
  char* qf = w;                                               // 4 MB fp8 frags
  char* pf = w + 4194304;                                     // 4 MB fp8 frags
  float* partial    = (float*)(w + 8388608);                  // 1 MB [8192][32]
  float* diag       = (float*)(w + 9437184);                  // 32 KB
  float* rowloss    = (float*)(w + 9437184 + 32768);          // 32 KB
  float* out = (float*)d_out;

  prep_k<<<NROWS / 16, 256, 0, stream>>>(q, p, qf, pf, diag);
  gemm_lse_k<<<256, 512, 0, stream>>>(qf, pf, partial);
  rowloss_k<<<NROWS / 256, 256, 0, stream>>>(partial, diag, rowloss);
  final_k<<<1, 1024, 0, stream>>>(rowloss, out);
}